// Round 2
// baseline (4403.262 us; speedup 1.0000x reference)
//
#include <hip/hip_runtime.h>
#include <cstdint>
#include <cstddef>

typedef unsigned short ushort_t;
typedef short bf16x8 __attribute__((ext_vector_type(8)));
typedef float f32x4 __attribute__((ext_vector_type(4)));

__device__ __forceinline__ float bf2f(ushort_t h) {
  union { unsigned u; float f; } v; v.u = ((unsigned)h) << 16; return v.f;
}
__device__ __forceinline__ ushort_t f2bf(float f) {
  union { float f; unsigned u; } v; v.f = f;
  unsigned u = v.u;
  return (ushort_t)((u + 0x7fffu + ((u >> 16) & 1u)) >> 16);
}

// ---------------------------------------------------------------------------
// Weight prep: (CO, C, KS2) f32 -> (CO, KS2, C) bf16   (tap-major K order)
// ---------------------------------------------------------------------------
__global__ __launch_bounds__(256) void wprep(const float* __restrict__ in,
                                             ushort_t* __restrict__ out,
                                             int CO, int C, int KS2) {
  int idx = blockIdx.x * 256 + threadIdx.x;
  int total = CO * C * KS2;
  if (idx >= total) return;
  int co  = idx / (C * KS2);
  int rem = idx - co * (C * KS2);
  int tap = rem / C;
  int c   = rem - tap * C;
  out[idx] = f2bf(in[(size_t)co * C * KS2 + (size_t)c * KS2 + tap]);
}

// ---------------------------------------------------------------------------
// Bilinear 2x upsample (align_corners=False), out bf16
// ---------------------------------------------------------------------------
template <bool IN_BF16>
__global__ __launch_bounds__(256) void upsample2x(const void* __restrict__ in_,
                                                  ushort_t* __restrict__ out,
                                                  int BC, int IH, int IW) {
  int OW = 2 * IW, OH = 2 * IH;
  int idx = blockIdx.x * 256 + threadIdx.x;
  int total = BC * OH * OW;
  if (idx >= total) return;
  int xo = idx % OW;
  int rest = idx / OW;
  int yo = rest % OH;
  int bc = rest / OH;
  int jy = yo >> 1, jx = xo >> 1;
  int y0, y1, x0, x1;
  float wy0, wy1, wx0, wx1;
  if (yo & 1) { y0 = jy; y1 = (jy + 1 < IH) ? jy + 1 : IH - 1; wy0 = 0.75f; wy1 = 0.25f; }
  else        { y0 = (jy - 1 > 0) ? jy - 1 : 0; y1 = jy; wy0 = 0.25f; wy1 = 0.75f; }
  if (xo & 1) { x0 = jx; x1 = (jx + 1 < IW) ? jx + 1 : IW - 1; wx0 = 0.75f; wx1 = 0.25f; }
  else        { x0 = (jx - 1 > 0) ? jx - 1 : 0; x1 = jx; wx0 = 0.25f; wx1 = 0.75f; }
  float v;
  if (IN_BF16) {
    const ushort_t* p = (const ushort_t*)in_ + (size_t)bc * IH * IW;
    v = wy0 * (wx0 * bf2f(p[y0 * IW + x0]) + wx1 * bf2f(p[y0 * IW + x1])) +
        wy1 * (wx0 * bf2f(p[y1 * IW + x0]) + wx1 * bf2f(p[y1 * IW + x1]));
  } else {
    const float* p = (const float*)in_ + (size_t)bc * IH * IW;
    v = wy0 * (wx0 * p[y0 * IW + x0] + wx1 * p[y0 * IW + x1]) +
        wy1 * (wx0 * p[y1 * IW + x0] + wx1 * p[y1 * IW + x1]);
  }
  out[idx] = f2bf(v);
}

// ---------------------------------------------------------------------------
// Text GEMM (fp32): t[m][n] = word_flat[m][:] . txt_w[n][:] + txt_b[n]
//   m = nc*16 + b  (2048 rows), n in [0, 2305)
//   n < 2304: c = n/9, tap = n%9 -> wkbuf[((b*128+nc)*2304) + tap*256 + c] (bf16)
//   n == 2304: dynbias[m] (f32)
// ---------------------------------------------------------------------------
__global__ __launch_bounds__(256) void text_gemm(const float* __restrict__ word,
                                                 const float* __restrict__ tw,
                                                 const float* __restrict__ tb,
                                                 ushort_t* __restrict__ wkbuf,
                                                 float* __restrict__ dynbias) {
  __shared__ float As[128][17];
  __shared__ float Bs[128][17];
  const int tid = threadIdx.x;
  const int m0 = blockIdx.y * 128, n0 = blockIdx.x * 128;
  const int tm = tid >> 4, tn = tid & 15;
  float acc[8][8] = {};
  for (int k0 = 0; k0 < 768; k0 += 16) {
#pragma unroll
    for (int i = 0; i < 8; ++i) {
      int e = tid + i * 256;
      int row = e >> 4, ki = e & 15;
      As[row][ki] = word[(size_t)(m0 + row) * 768 + k0 + ki];
      int nr = n0 + row;
      Bs[row][ki] = (nr < 2305) ? tw[(size_t)nr * 768 + k0 + ki] : 0.f;
    }
    __syncthreads();
#pragma unroll
    for (int ki = 0; ki < 16; ++ki) {
      float av[8], bv[8];
#pragma unroll
      for (int i = 0; i < 8; ++i) av[i] = As[tm * 8 + i][ki];
#pragma unroll
      for (int j = 0; j < 8; ++j) bv[j] = Bs[tn + j * 16][ki];
#pragma unroll
      for (int i = 0; i < 8; ++i)
#pragma unroll
        for (int j = 0; j < 8; ++j) acc[i][j] = fmaf(av[i], bv[j], acc[i][j]);
    }
    __syncthreads();
  }
#pragma unroll
  for (int i = 0; i < 8; ++i) {
    int m = m0 + tm * 8 + i;
    int nc = m >> 4, bb = m & 15;
#pragma unroll
    for (int j = 0; j < 8; ++j) {
      int n = n0 + tn + j * 16;
      if (n >= 2305) continue;
      float v = acc[i][j] + tb[n];
      if (n < 2304) {
        int c = n / 9, tap = n - c * 9;
        wkbuf[((size_t)bb * 128 + nc) * 2304 + tap * 256 + c] = f2bf(v);
      } else {
        dynbias[m] = v;
      }
    }
  }
}

// ---------------------------------------------------------------------------
// Implicit-GEMM conv via MFMA 16x16x32 bf16.
//   in:  (B, C, H, W) bf16, zero-pad KS/2
//   wt:  (M, KS*KS, C) bf16  (tap-major K), or (B, M, KS*KS, C) if PIW
//   out: D[co][pix]
// EPI: 0 = BN+ReLU -> bf16   (p0..p3 = g,b,m,v)
//      1 = +bias[co] -> bf16 (p0 = bias)
//      2 = +p0[co*16+b] -> f32 (dynamic conv)
// Block: T threads (T/64 waves), tile BM x BN, each wave a 64x64 sub-tile.
// ---------------------------------------------------------------------------
template <int KS, int EPI, int BM, int BN, int TW, int TH, int NWN, int T, bool PIW>
__global__ __launch_bounds__(T) void conv_mfma(
    const ushort_t* __restrict__ in, const ushort_t* __restrict__ wt,
    const float* __restrict__ p0, const float* __restrict__ p1,
    const float* __restrict__ p2, const float* __restrict__ p3,
    ushort_t* __restrict__ outb, float* __restrict__ outf,
    int C, int H, int W, int M) {
  constexpr int BKP = 72;  // 144B row stride: stride%32dw==4 -> 2-way, free
  __shared__ ushort_t Asm[BM][BKP];
  __shared__ ushort_t Bsm[BN][BKP];

  const int tid = threadIdx.x;
  const int lane = tid & 63;
  const int wid = tid >> 6;
  const int tiles_x = W / TW;
  const int x0 = (blockIdx.x % tiles_x) * TW;
  const int y0 = (blockIdx.x / tiles_x) * TH;
  const int co0 = blockIdx.y * BM;
  const int b = blockIdx.z;
  const int HW = H * W;
  const long long K = (long long)C * KS * KS;

  const ushort_t* wp = wt + (PIW ? (size_t)b * M * K : 0);
  const ushort_t* ip = in + (size_t)b * C * HW;

  // B-staging mapping: thread -> (pixel sn, k-segment sh)
  const int sn = tid % BN;
  const int sh = tid / BN;
  constexpr int SEG = 64 * BN / T;
  const int syy = y0 + sn / TW;
  const int sxx = x0 + sn % TW;

  // fragment read offsets
  const int lr = lane & 15;
  const int lk = (lane >> 4) * 8;
  const int cow = (wid / NWN) * 64;
  const int pxw = (wid % NWN) * 64;

  f32x4 acc[4][4];
#pragma unroll
  for (int r = 0; r < 4; ++r)
#pragma unroll
    for (int q = 0; q < 4; ++q) acc[r][q] = (f32x4){0.f, 0.f, 0.f, 0.f};

  for (int tap = 0; tap < KS * KS; ++tap) {
    const int dy = (KS == 3) ? tap / 3 - 1 : 0;
    const int dx = (KS == 3) ? tap % 3 - 1 : 0;
    const int sy = syy + dy, sx = sxx + dx;
    const bool ok = (KS == 1) || ((unsigned)sy < (unsigned)H && (unsigned)sx < (unsigned)W);
    const long long sbase = (long long)(sh * SEG) * HW + (long long)sy * W + sx;

    for (int c0 = 0; c0 < C; c0 += 64) {
      const int k0 = tap * C + c0;
      // --- stage A (weights): BM x 64 as bf16x8 vectors ---
#pragma unroll
      for (int i = 0; i < BM * 8 / T; ++i) {
        int e = tid + i * T;
        int row = e >> 3, k8 = e & 7;
        bf16x8 v = *(const bf16x8*)(wp + (size_t)(co0 + row) * K + k0 + k8 * 8);
        *(bf16x8*)&Asm[row][k8 * 8] = v;
      }
      // --- stage B (im2col, uniform shift per chunk): BN x 64 ---
      {
        const long long cb = sbase + (long long)c0 * HW;
#pragma unroll
        for (int i = 0; i < SEG; ++i) {
          ushort_t v = ok ? ip[cb + (long long)i * HW] : (ushort_t)0;
          Bsm[sn][sh * SEG + i] = v;
        }
      }
      __syncthreads();
      // --- MFMA: 2 k-steps of 32 ---
#pragma unroll
      for (int ks = 0; ks < 64; ks += 32) {
        bf16x8 af[4], bfr[4];
#pragma unroll
        for (int r = 0; r < 4; ++r)
          af[r] = *(const bf16x8*)&Asm[cow + r * 16 + lr][ks + lk];
#pragma unroll
        for (int q = 0; q < 4; ++q)
          bfr[q] = *(const bf16x8*)&Bsm[pxw + q * 16 + lr][ks + lk];
#pragma unroll
        for (int r = 0; r < 4; ++r)
#pragma unroll
          for (int q = 0; q < 4; ++q)
            acc[r][q] = __builtin_amdgcn_mfma_f32_16x16x32_bf16(af[r], bfr[q], acc[r][q], 0, 0, 0);
      }
      __syncthreads();
    }
  }

  // --- epilogue: C/D layout col=lane&15, row=(lane>>4)*4+j ---
  const int col = lane & 15;
  const int rb = (lane >> 4) * 4;
#pragma unroll
  for (int r = 0; r < 4; ++r) {
#pragma unroll
    for (int q = 0; q < 4; ++q) {
      int n = pxw + q * 16 + col;
      int px = x0 + (n % TW), py = y0 + (n / TW);
#pragma unroll
      for (int j = 0; j < 4; ++j) {
        int co = co0 + cow + r * 16 + rb + j;
        float v = acc[r][q][j];
        if (EPI == 0) {
          float inv = p0[co] * rsqrtf(p3[co] + 1e-5f);
          v = v * inv + (p1[co] - p2[co] * inv);
          v = fmaxf(v, 0.f);
          outb[((size_t)b * M + co) * HW + py * W + px] = f2bf(v);
        } else if (EPI == 1) {
          v += p0[co];
          outb[((size_t)b * M + co) * HW + py * W + px] = f2bf(v);
        } else {
          v += p0[co * 16 + b];
          outf[((size_t)b * M + co) * HW + py * W + px] = v;
        }
      }
    }
  }
}

// Diagnostic fallback: ws too small -> zero output (passed=false w/ big absmax,
// distinguishable from a crash).
__global__ __launch_bounds__(256) void fill_zero(float* __restrict__ p, int n) {
  int i = blockIdx.x * 256 + threadIdx.x;
  if (i < n) p[i] = 0.f;
}

// ---------------------------------------------------------------------------
extern "C" void kernel_launch(void* const* d_in, const int* in_sizes, int n_in,
                              void* d_out, int out_size, void* d_ws, size_t ws_size,
                              hipStream_t stream) {
  (void)in_sizes; (void)n_in;
  const float* x       = (const float*)d_in[0];
  const float* word    = (const float*)d_in[1];
  const float* conv1_w = (const float*)d_in[2];
  const float* bn1_g   = (const float*)d_in[3];
  const float* bn1_b   = (const float*)d_in[4];
  const float* bn1_m   = (const float*)d_in[5];
  const float* bn1_v   = (const float*)d_in[6];
  const float* conv2_w = (const float*)d_in[7];
  const float* bn2_g   = (const float*)d_in[8];
  const float* bn2_b   = (const float*)d_in[9];
  const float* bn2_m   = (const float*)d_in[10];
  const float* bn2_v   = (const float*)d_in[11];
  const float* conv3_w = (const float*)d_in[12];
  const float* conv3_b = (const float*)d_in[13];
  const float* txt_w   = (const float*)d_in[14];
  const float* txt_b   = (const float*)d_in[15];
  float* out = (float*)d_out;

  char* ws = (char*)d_ws;
  size_t off = 0;
  auto alloc = [&](size_t bytes) -> void* {
    void* p = ws + off;
    off += bytes;
    off = (off + 255) & ~(size_t)255;
    return p;
  };
  // Region P0 (151 MB): up1 (37.7 MB, dead after conv1) -> up2 (151 MB, dead
  // after conv2) -> vb (75.5 MB). a1 separate (live across upsample2).
  // a2 (75.5 MB bf16) lives in d_out (75.5 MB f32 region, dead until dynconv).
  ushort_t* P0  = (ushort_t*)alloc((size_t)16 * 512 * 96 * 96 * 2);  // 150,994,944
  ushort_t* up1 = P0;
  ushort_t* up2 = P0;
  ushort_t* vb  = P0;
  ushort_t* a1  = (ushort_t*)alloc((size_t)16 * 512 * 48 * 48 * 2);  // 37,748,736
  ushort_t* w1b = (ushort_t*)alloc((size_t)512 * 4608 * 2);
  ushort_t* w2b = (ushort_t*)alloc((size_t)256 * 4608 * 2);
  ushort_t* w3b = (ushort_t*)alloc((size_t)256 * 256 * 2);
  ushort_t* wkb = (ushort_t*)alloc((size_t)16 * 128 * 2304 * 2);
  float*    dyb = (float*)alloc((size_t)2048 * 4);
  ushort_t* a2  = (ushort_t*)d_out;  // exactly 75,497,472 bytes, reused

  if (ws_size < off) {
    // Workspace too small for this plan: emit zeros as a diagnostic signal.
    fill_zero<<<(out_size + 255) / 256, 256, 0, stream>>>(out, out_size);
    return;
  }

  // weight prep (cast + tap-major transpose)
  wprep<<<(512 * 4608 + 255) / 256, 256, 0, stream>>>(conv1_w, w1b, 512, 512, 9);
  wprep<<<(256 * 4608 + 255) / 256, 256, 0, stream>>>(conv2_w, w2b, 256, 512, 9);
  wprep<<<(256 * 256 + 255) / 256, 256, 0, stream>>>(conv3_w, w3b, 256, 256, 1);

  // text branch (f32 GEMM -> bf16 dyn filters + f32 dyn bias)
  text_gemm<<<dim3(19, 16), 256, 0, stream>>>(word, txt_w, txt_b, wkb, dyb);

  // vis branch
  {
    int n = 16 * 512 * 48 * 48;
    upsample2x<false><<<(n + 255) / 256, 256, 0, stream>>>(x, up1, 16 * 512, 24, 24);
  }
  conv_mfma<3, 0, 256, 128, 16, 8, 2, 512, false>
      <<<dim3(18, 2, 16), 512, 0, stream>>>(up1, w1b, bn1_g, bn1_b, bn1_m, bn1_v,
                                            a1, nullptr, 512, 48, 48, 512);
  {
    int n = 16 * 512 * 96 * 96;
    upsample2x<true><<<(n + 255) / 256, 256, 0, stream>>>(a1, up2, 16 * 512, 48, 48);
  }
  conv_mfma<3, 0, 256, 128, 32, 4, 2, 512, false>
      <<<dim3(72, 1, 16), 512, 0, stream>>>(up2, w2b, bn2_g, bn2_b, bn2_m, bn2_v,
                                            a2, nullptr, 512, 96, 96, 256);
  conv_mfma<1, 1, 256, 128, 32, 4, 2, 512, false>
      <<<dim3(72, 1, 16), 512, 0, stream>>>(a2, w3b, conv3_b, nullptr, nullptr, nullptr,
                                            vb, nullptr, 256, 96, 96, 256);
  // dynamic conv: per-image filters, out f32
  conv_mfma<3, 2, 128, 128, 32, 4, 2, 256, true>
      <<<dim3(72, 1, 16), 256, 0, stream>>>(vb, wkb, dyb, nullptr, nullptr, nullptr,
                                            nullptr, out, 256, 96, 96, 128);
}

// Round 3
// 1730.982 us; speedup vs baseline: 2.5438x; 2.5438x over previous
//
#include <hip/hip_runtime.h>
#include <cstdint>
#include <cstddef>

typedef unsigned short ushort_t;
typedef short bf16x8 __attribute__((ext_vector_type(8)));
typedef float f32x4 __attribute__((ext_vector_type(4)));

__device__ __forceinline__ float bf2f(ushort_t h) {
  union { unsigned u; float f; } v; v.u = ((unsigned)h) << 16; return v.f;
}
__device__ __forceinline__ ushort_t f2bf(float f) {
  union { float f; unsigned u; } v; v.f = f;
  unsigned u = v.u;
  return (ushort_t)((u + 0x7fffu + ((u >> 16) & 1u)) >> 16);
}

// async 16B/lane global->LDS DMA (wave-uniform LDS base, per-lane global src)
#define GLOAD16(g, l)                                                         \
  __builtin_amdgcn_global_load_lds(                                           \
      (const __attribute__((address_space(1))) void*)(g),                     \
      (__attribute__((address_space(3))) void*)(l), 16, 0, 0)

// ---------------------------------------------------------------------------
// Weight prep: (CO, C, KS2) f32 -> (CO, KS2, C) bf16   (tap-major K order)
// ---------------------------------------------------------------------------
__global__ __launch_bounds__(256) void wprep(const float* __restrict__ in,
                                             ushort_t* __restrict__ out,
                                             int CO, int C, int KS2) {
  int idx = blockIdx.x * 256 + threadIdx.x;
  int total = CO * C * KS2;
  if (idx >= total) return;
  int co  = idx / (C * KS2);
  int rem = idx - co * (C * KS2);
  int tap = rem / C;
  int c   = rem - tap * C;
  out[idx] = f2bf(in[(size_t)co * C * KS2 + (size_t)c * KS2 + tap]);
}

// ---------------------------------------------------------------------------
// Zero the 1-px border of a padded NHWC buffer (ws is re-poisoned every call)
// ---------------------------------------------------------------------------
__global__ __launch_bounds__(256) void border_zero(ushort_t* __restrict__ buf,
                                                   int B, int PH, int PW, int C) {
  int nb = 2 * PW + 2 * (PH - 2);
  long long total = (long long)B * nb * C;
  long long idx = (long long)blockIdx.x * 256 + threadIdx.x;
  if (idx >= total) return;
  int c = (int)(idx % C);
  long long r = idx / C;
  int bp = (int)(r % nb);
  int b = (int)(r / nb);
  int y, x;
  if (bp < PW) { y = 0; x = bp; }
  else if (bp < 2 * PW) { y = PH - 1; x = bp - PW; }
  else { int e = bp - 2 * PW; y = 1 + (e >> 1); x = (e & 1) ? PW - 1 : 0; }
  buf[((size_t)(b * PH + y) * PW + x) * C + c] = 0;
}

// ---------------------------------------------------------------------------
// Upsample 2x bilinear (align_corners=False)
// up1: in f32 NCHW (16,512,24,24) -> out bf16 NHWC padded (16,50,50,512) interior
// ---------------------------------------------------------------------------
__global__ __launch_bounds__(256) void upsample1(const float* __restrict__ in,
                                                 ushort_t* __restrict__ out) {
  int idx = blockIdx.x * 256 + threadIdx.x;
  if (idx >= 16 * 48 * 48 * 512) return;
  int c = idx & 511;
  int px = idx >> 9;
  int x = px % 48; int rest = px / 48; int y = rest % 48; int b = rest / 48;
  int jy = y >> 1, jx = x >> 1;
  int y0, y1, x0, x1; float wy0, wy1, wx0, wx1;
  if (y & 1) { y0 = jy; y1 = (jy + 1 < 24) ? jy + 1 : 23; wy0 = 0.75f; wy1 = 0.25f; }
  else       { y0 = (jy > 0) ? jy - 1 : 0; y1 = jy; wy0 = 0.25f; wy1 = 0.75f; }
  if (x & 1) { x0 = jx; x1 = (jx + 1 < 24) ? jx + 1 : 23; wx0 = 0.75f; wx1 = 0.25f; }
  else       { x0 = (jx > 0) ? jx - 1 : 0; x1 = jx; wx0 = 0.25f; wx1 = 0.75f; }
  const float* p = in + ((size_t)b * 512 + c) * 576;
  float v = wy0 * (wx0 * p[y0 * 24 + x0] + wx1 * p[y0 * 24 + x1]) +
            wy1 * (wx0 * p[y1 * 24 + x0] + wx1 * p[y1 * 24 + x1]);
  out[(((size_t)b * 50 + y + 1) * 50 + (x + 1)) * 512 + c] = f2bf(v);
}

// up2: in bf16 NHWC (16,48,48,512) -> out bf16 NHWC padded (16,98,98,512) interior
__global__ __launch_bounds__(256) void upsample2(const ushort_t* __restrict__ in,
                                                 ushort_t* __restrict__ out) {
  int idx = blockIdx.x * 256 + threadIdx.x;
  if (idx >= 16 * 96 * 96 * 512) return;
  int c = idx & 511;
  int px = idx >> 9;
  int x = px % 96; int rest = px / 96; int y = rest % 96; int b = rest / 96;
  int jy = y >> 1, jx = x >> 1;
  int y0, y1, x0, x1; float wy0, wy1, wx0, wx1;
  if (y & 1) { y0 = jy; y1 = (jy + 1 < 48) ? jy + 1 : 47; wy0 = 0.75f; wy1 = 0.25f; }
  else       { y0 = (jy > 0) ? jy - 1 : 0; y1 = jy; wy0 = 0.25f; wy1 = 0.75f; }
  if (x & 1) { x0 = jx; x1 = (jx + 1 < 48) ? jx + 1 : 47; wx0 = 0.75f; wx1 = 0.25f; }
  else       { x0 = (jx > 0) ? jx - 1 : 0; x1 = jx; wx0 = 0.25f; wx1 = 0.75f; }
  const ushort_t* p = in + (size_t)b * 48 * 48 * 512 + c;
  float v = wy0 * (wx0 * bf2f(p[(y0 * 48 + x0) * 512]) + wx1 * bf2f(p[(y0 * 48 + x1) * 512])) +
            wy1 * (wx0 * bf2f(p[(y1 * 48 + x0) * 512]) + wx1 * bf2f(p[(y1 * 48 + x1) * 512]));
  out[(((size_t)b * 98 + y + 1) * 98 + (x + 1)) * 512 + c] = f2bf(v);
}

// ---------------------------------------------------------------------------
// Text GEMM (fp32) -> per-(word,image) bf16 filters (B, Nc, 9, 256) + f32 bias
// ---------------------------------------------------------------------------
__global__ __launch_bounds__(256) void text_gemm(const float* __restrict__ word,
                                                 const float* __restrict__ tw,
                                                 const float* __restrict__ tb,
                                                 ushort_t* __restrict__ wkbuf,
                                                 float* __restrict__ dynbias) {
  __shared__ float As[128][17];
  __shared__ float Bs[128][17];
  const int tid = threadIdx.x;
  const int m0 = blockIdx.y * 128, n0 = blockIdx.x * 128;
  const int tm = tid >> 4, tn = tid & 15;
  float acc[8][8] = {};
  for (int k0 = 0; k0 < 768; k0 += 16) {
#pragma unroll
    for (int i = 0; i < 8; ++i) {
      int e = tid + i * 256;
      int row = e >> 4, ki = e & 15;
      As[row][ki] = word[(size_t)(m0 + row) * 768 + k0 + ki];
      int nr = n0 + row;
      Bs[row][ki] = (nr < 2305) ? tw[(size_t)nr * 768 + k0 + ki] : 0.f;
    }
    __syncthreads();
#pragma unroll
    for (int ki = 0; ki < 16; ++ki) {
      float av[8], bv[8];
#pragma unroll
      for (int i = 0; i < 8; ++i) av[i] = As[tm * 8 + i][ki];
#pragma unroll
      for (int j = 0; j < 8; ++j) bv[j] = Bs[tn + j * 16][ki];
#pragma unroll
      for (int i = 0; i < 8; ++i)
#pragma unroll
        for (int j = 0; j < 8; ++j) acc[i][j] = fmaf(av[i], bv[j], acc[i][j]);
    }
    __syncthreads();
  }
#pragma unroll
  for (int i = 0; i < 8; ++i) {
    int m = m0 + tm * 8 + i;
    int nc = m >> 4, bb = m & 15;
#pragma unroll
    for (int j = 0; j < 8; ++j) {
      int n = n0 + tn + j * 16;
      if (n >= 2305) continue;
      float v = acc[i][j] + tb[n];
      if (n < 2304) {
        int c = n / 9, tap = n - c * 9;
        wkbuf[((size_t)bb * 128 + nc) * 2304 + tap * 256 + c] = f2bf(v);
      } else {
        dynbias[m] = v;
      }
    }
  }
}

// ---------------------------------------------------------------------------
// NHWC implicit-GEMM conv, MFMA 16x16x32 bf16, global_load_lds staging,
// XOR-swizzled LDS (slot ^= row&7; linear dest + inverse-swizzled source).
//   in : NHWC, spatially pre-padded by 1 if KS==3 (zero border)
//   wt : (M, KS*KS, C) bf16, or (B, M, KS*KS, C) if PIW
// Block: 256 thr (4 waves), tile BM x BN, wave tile (BM/MW) x (BN/NW) = 128x64.
// EPI: 0 BN+ReLU->bf16 NHWC; 1 +bias->bf16 NHWC (OPAD: padded interior);
//      2 +dynbias->f32 NCHW.
// ---------------------------------------------------------------------------
template <int KS, int EPI, int BM, int BN, int MW, int NW, int H, int W, int C,
          int MOUT, bool PIW, bool OPAD>
__global__ __launch_bounds__(256, 2) void conv_mfma(
    const ushort_t* __restrict__ in, const ushort_t* __restrict__ wt,
    const float* __restrict__ p0, const float* __restrict__ p1,
    const float* __restrict__ p2, const float* __restrict__ p3,
    ushort_t* __restrict__ outb, float* __restrict__ outf) {
  constexpr int WAVES = 4;
  constexpr int AINST = BM / (8 * WAVES);
  constexpr int BINST = BN / (8 * WAVES);
  constexpr int MR = BM / MW / 16;
  constexpr int NR = BN / NW / 16;
  constexpr int KK = KS * KS;
  constexpr int PHI = (KS == 3) ? H + 2 : H;
  constexpr int PWI = (KS == 3) ? W + 2 : W;
  __shared__ ushort_t Asm[BM * 64];
  __shared__ ushort_t Bsm[BN * 64];

  const int tid = threadIdx.x;
  const int lane = tid & 63;
  const int wid = tid >> 6;
  const int p0t = blockIdx.x * BN;
  const int co0 = blockIdx.y * BM;
  const int b = blockIdx.z;

  // inverse swizzle on the global source; LDS dest stays lane-linear
  const int soff = ((lane & 7) ^ ((lane >> 3) & 7)) * 16;

  const char* wbase = (const char*)wt + (PIW ? (size_t)b * MOUT * KK * C * 2 : 0);
  const char* aptr[AINST];
#pragma unroll
  for (int j = 0; j < AINST; ++j) {
    int arow = wid * (AINST * 8) + j * 8 + (lane >> 3);
    aptr[j] = wbase + (size_t)(co0 + arow) * ((size_t)KK * C * 2) + soff;
  }
  const char* ibase = (const char*)in + (size_t)b * PHI * PWI * C * 2;
  const char* bptr[BINST];
#pragma unroll
  for (int i = 0; i < BINST; ++i) {
    int brow = wid * (BINST * 8) + i * 8 + (lane >> 3);
    int p = p0t + brow;
    int y = p / W, x = p % W;
    int off = (KS == 3) ? ((y + 1) * PWI + (x + 1)) : (y * W + x);
    bptr[i] = ibase + (size_t)off * C * 2 + soff;
  }

  const int lr = lane & 15, hi = lane >> 4;
  const int cow = (wid / NW) * (BM / MW);
  const int pxw = (wid % NW) * (BN / NW);
  int aoff[MR], boff[NR];
#pragma unroll
  for (int r = 0; r < MR; ++r) {
    int row = cow + r * 16 + lr;
    aoff[r] = row * 128 + ((hi ^ (row & 7)) * 16);
  }
#pragma unroll
  for (int q = 0; q < NR; ++q) {
    int row = pxw + q * 16 + lr;
    boff[q] = row * 128 + ((hi ^ (row & 7)) * 16);
  }

  f32x4 acc[MR][NR];
#pragma unroll
  for (int r = 0; r < MR; ++r)
#pragma unroll
    for (int q = 0; q < NR; ++q) acc[r][q] = (f32x4){0.f, 0.f, 0.f, 0.f};

#pragma unroll 1
  for (int tap = 0; tap < KK; ++tap) {
    const int toff = (KS == 3) ? ((tap / 3 - 1) * PWI + (tap % 3 - 1)) * C * 2 : 0;
#pragma unroll 1
    for (int c0 = 0; c0 < C; c0 += 64) {
      const int koff = (tap * C + c0) * 2;
#pragma unroll
      for (int j = 0; j < AINST; ++j)
        GLOAD16(aptr[j] + koff, (char*)Asm + (wid * AINST + j) * 1024);
#pragma unroll
      for (int i = 0; i < BINST; ++i)
        GLOAD16(bptr[i] + toff + c0 * 2, (char*)Bsm + (wid * BINST + i) * 1024);
      __syncthreads();
#pragma unroll
      for (int ks = 0; ks < 2; ++ks) {
        const int kx = ks * 64;  // slot^4 => byte^64
        bf16x8 af[MR], bfv[NR];
#pragma unroll
        for (int r = 0; r < MR; ++r)
          af[r] = *(const bf16x8*)((const char*)Asm + (aoff[r] ^ kx));
#pragma unroll
        for (int q = 0; q < NR; ++q)
          bfv[q] = *(const bf16x8*)((const char*)Bsm + (boff[q] ^ kx));
#pragma unroll
        for (int r = 0; r < MR; ++r)
#pragma unroll
          for (int q = 0; q < NR; ++q)
            acc[r][q] = __builtin_amdgcn_mfma_f32_16x16x32_bf16(af[r], bfv[q], acc[r][q], 0, 0, 0);
      }
      __syncthreads();
    }
  }

  // epilogue: D col=lane&15 (pixel), row=(lane>>4)*4+j (co)
#pragma unroll
  for (int r = 0; r < MR; ++r) {
    const int co = co0 + cow + r * 16 + hi * 4;
    float sc[4], sh[4];
#pragma unroll
    for (int j = 0; j < 4; ++j) {
      if (EPI == 0) {
        float inv = p0[co + j] * rsqrtf(p3[co + j] + 1e-5f);
        sc[j] = inv; sh[j] = p1[co + j] - p2[co + j] * inv;
      } else if (EPI == 1) {
        sc[j] = 1.f; sh[j] = p0[co + j];
      }
    }
#pragma unroll
    for (int q = 0; q < NR; ++q) {
      int p = p0t + pxw + q * 16 + lr;
      int y = p / W, x = p % W;
      if (EPI == 2) {
#pragma unroll
        for (int j = 0; j < 4; ++j) {
          float v = acc[r][q][j] + p0[(co + j) * 16 + b];
          outf[(((size_t)b * MOUT + co + j) * H + y) * W + x] = v;
        }
      } else {
        ushort_t pk[4];
#pragma unroll
        for (int j = 0; j < 4; ++j) {
          float v = acc[r][q][j] * sc[j] + sh[j];
          if (EPI == 0) v = fmaxf(v, 0.f);
          pk[j] = f2bf(v);
        }
        size_t oidx = OPAD
            ? (((size_t)b * (H + 2) + y + 1) * (W + 2) + x + 1) * MOUT + co
            : (((size_t)b * H + y) * W + x) * MOUT + co;
        *(uint2*)&outb[oidx] = *(const uint2*)pk;
      }
    }
  }
}

__global__ __launch_bounds__(256) void fill_zero(float* __restrict__ p, int n) {
  int i = blockIdx.x * 256 + threadIdx.x;
  if (i < n) p[i] = 0.f;
}

// ---------------------------------------------------------------------------
extern "C" void kernel_launch(void* const* d_in, const int* in_sizes, int n_in,
                              void* d_out, int out_size, void* d_ws, size_t ws_size,
                              hipStream_t stream) {
  (void)in_sizes; (void)n_in;
  const float* x       = (const float*)d_in[0];
  const float* word    = (const float*)d_in[1];
  const float* conv1_w = (const float*)d_in[2];
  const float* bn1_g   = (const float*)d_in[3];
  const float* bn1_b   = (const float*)d_in[4];
  const float* bn1_m   = (const float*)d_in[5];
  const float* bn1_v   = (const float*)d_in[6];
  const float* conv2_w = (const float*)d_in[7];
  const float* bn2_g   = (const float*)d_in[8];
  const float* bn2_b   = (const float*)d_in[9];
  const float* bn2_m   = (const float*)d_in[10];
  const float* bn2_v   = (const float*)d_in[11];
  const float* conv3_w = (const float*)d_in[12];
  const float* conv3_b = (const float*)d_in[13];
  const float* txt_w   = (const float*)d_in[14];
  const float* txt_b   = (const float*)d_in[15];
  float* out = (float*)d_out;

  char* ws = (char*)d_ws;
  size_t off = 0;
  auto alloc = [&](size_t bytes) -> void* {
    void* p = ws + off;
    off += bytes;
    off = (off + 255) & ~(size_t)255;
    return p;
  };
  // P0: up1 (16,50,50,512) -> up2 (16,98,98,512) -> vb (16,98,98,256); all NHWC
  ushort_t* P0  = (ushort_t*)alloc((size_t)16 * 98 * 98 * 512 * 2);  // 157.35 MB
  ushort_t* up1 = P0;
  ushort_t* up2 = P0;
  ushort_t* vb  = P0;
  ushort_t* a1  = (ushort_t*)alloc((size_t)16 * 48 * 48 * 512 * 2);  // 37.75 MB
  ushort_t* w1b = (ushort_t*)alloc((size_t)512 * 4608 * 2);
  ushort_t* w2b = (ushort_t*)alloc((size_t)256 * 4608 * 2);
  ushort_t* w3b = (ushort_t*)alloc((size_t)256 * 256 * 2);
  ushort_t* wkb = (ushort_t*)alloc((size_t)16 * 128 * 2304 * 2);
  float*    dyb = (float*)alloc((size_t)2048 * 4);
  ushort_t* a2  = (ushort_t*)d_out;  // (16,96,96,256) bf16 == 75,497,472 B exact

  if (ws_size < off) {
    fill_zero<<<(out_size + 255) / 256, 256, 0, stream>>>(out, out_size);
    return;
  }

  // prep
  wprep<<<(512 * 4608 + 255) / 256, 256, 0, stream>>>(conv1_w, w1b, 512, 512, 9);
  wprep<<<(256 * 4608 + 255) / 256, 256, 0, stream>>>(conv2_w, w2b, 256, 512, 9);
  wprep<<<(256 * 256 + 255) / 256, 256, 0, stream>>>(conv3_w, w3b, 256, 256, 1);
  text_gemm<<<dim3(19, 16), 256, 0, stream>>>(word, txt_w, txt_b, wkb, dyb);

  // up1 (border + interior)
  {
    long long nbz = (long long)16 * (2 * 50 + 2 * 48) * 512;
    border_zero<<<(int)((nbz + 255) / 256), 256, 0, stream>>>(up1, 16, 50, 50, 512);
    int n = 16 * 48 * 48 * 512;
    upsample1<<<(n + 255) / 256, 256, 0, stream>>>(x, up1);
  }
  // conv1: (16,50,50,512) -> a1 (16,48,48,512)
  conv_mfma<3, 0, 256, 128, 2, 2, 48, 48, 512, 512, false, false>
      <<<dim3(18, 2, 16), 256, 0, stream>>>(up1, w1b, bn1_g, bn1_b, bn1_m, bn1_v,
                                            a1, nullptr);
  // up2 (border + interior)  [P0 reused; up1 dead]
  {
    long long nbz = (long long)16 * (2 * 98 + 2 * 96) * 512;
    border_zero<<<(int)((nbz + 255) / 256), 256, 0, stream>>>(up2, 16, 98, 98, 512);
    int n = 16 * 96 * 96 * 512;
    upsample2<<<(n + 255) / 256, 256, 0, stream>>>(a1, up2);
  }
  // conv2: (16,98,98,512) -> a2 (16,96,96,256) in d_out
  conv_mfma<3, 0, 256, 128, 2, 2, 96, 96, 512, 256, false, false>
      <<<dim3(72, 1, 16), 256, 0, stream>>>(up2, w2b, bn2_g, bn2_b, bn2_m, bn2_v,
                                            a2, nullptr);
  // vb border  [P0 reused; up2 dead]
  {
    long long nbz = (long long)16 * (2 * 98 + 2 * 96) * 256;
    border_zero<<<(int)((nbz + 255) / 256), 256, 0, stream>>>(vb, 16, 98, 98, 256);
  }
  // conv3 1x1: a2 -> vb (16,98,98,256) padded interior
  conv_mfma<1, 1, 256, 128, 2, 2, 96, 96, 256, 256, false, true>
      <<<dim3(72, 1, 16), 256, 0, stream>>>(a2, w3b, conv3_b, nullptr, nullptr, nullptr,
                                            vb, nullptr);
  // dynamic conv: vb -> out (B,128,96,96) f32 NCHW
  conv_mfma<3, 2, 128, 256, 1, 4, 96, 96, 256, 128, true, false>
      <<<dim3(36, 1, 16), 256, 0, stream>>>(vb, wkb, dyb, nullptr, nullptr, nullptr,
                                            nullptr, out);
}

// Round 6
// 1281.827 us; speedup vs baseline: 3.4351x; 1.3504x over previous
//
#include <hip/hip_runtime.h>
#include <cstdint>
#include <cstddef>

typedef unsigned short ushort_t;
typedef short bf16x8 __attribute__((ext_vector_type(8)));
typedef float f32x4 __attribute__((ext_vector_type(4)));

__device__ __forceinline__ float bf2f(ushort_t h) {
  union { unsigned u; float f; } v; v.u = ((unsigned)h) << 16; return v.f;
}
__device__ __forceinline__ ushort_t f2bf(float f) {
  union { float f; unsigned u; } v; v.f = f;
  unsigned u = v.u;
  return (ushort_t)((u + 0x7fffu + ((u >> 16) & 1u)) >> 16);
}

// async 16B/lane global->LDS DMA (wave-uniform LDS base, per-lane global src)
#define GLOAD16(g, l)                                                         \
  __builtin_amdgcn_global_load_lds(                                           \
      (const __attribute__((address_space(1))) void*)(g),                     \
      (__attribute__((address_space(3))) void*)(l), 16, 0, 0)

// ---------------------------------------------------------------------------
// Weight prep: (CO, C, KS2) f32 -> (CO, KS2, C) bf16   (tap-major K order)
// ---------------------------------------------------------------------------
__global__ __launch_bounds__(256) void wprep(const float* __restrict__ in,
                                             ushort_t* __restrict__ out,
                                             int CO, int C, int KS2) {
  int idx = blockIdx.x * 256 + threadIdx.x;
  int total = CO * C * KS2;
  if (idx >= total) return;
  int co  = idx / (C * KS2);
  int rem = idx - co * (C * KS2);
  int tap = rem / C;
  int c   = rem - tap * C;
  out[idx] = f2bf(in[(size_t)co * C * KS2 + (size_t)c * KS2 + tap]);
}

// ---------------------------------------------------------------------------
// f32 -> (hi bf16, lo bf16) split; rows >= rows_in are zero (N padding)
// ---------------------------------------------------------------------------
__global__ __launch_bounds__(256) void fsplit(const float* __restrict__ in,
                                              ushort_t* __restrict__ hi,
                                              ushort_t* __restrict__ lo,
                                              int rows_in, long long total) {
  long long idx = (long long)blockIdx.x * 256 + threadIdx.x;
  if (idx >= total) return;
  long long r = idx / 768;
  float x = (r < rows_in) ? in[idx] : 0.f;
  ushort_t h = f2bf(x);
  hi[idx] = h;
  lo[idx] = f2bf(x - bf2f(h));
}

// ---------------------------------------------------------------------------
// Zero the 1-px border of a padded NHWC buffer (ws is re-poisoned every call)
// ---------------------------------------------------------------------------
__global__ __launch_bounds__(256) void border_zero(ushort_t* __restrict__ buf,
                                                   int B, int PH, int PW, int C) {
  int nb = 2 * PW + 2 * (PH - 2);
  long long total = (long long)B * nb * C;
  long long idx = (long long)blockIdx.x * 256 + threadIdx.x;
  if (idx >= total) return;
  int c = (int)(idx % C);
  long long r = idx / C;
  int bp = (int)(r % nb);
  int b = (int)(r / nb);
  int y, x;
  if (bp < PW) { y = 0; x = bp; }
  else if (bp < 2 * PW) { y = PH - 1; x = bp - PW; }
  else { int e = bp - 2 * PW; y = 1 + (e >> 1); x = (e & 1) ? PW - 1 : 0; }
  buf[((size_t)(b * PH + y) * PW + x) * C + c] = 0;
}

// ---------------------------------------------------------------------------
// Upsample 2x bilinear (align_corners=False)
// up1: in f32 NCHW (16,512,24,24) -> out bf16 NHWC padded (16,50,50,512) interior
// ---------------------------------------------------------------------------
__global__ __launch_bounds__(256) void upsample1(const float* __restrict__ in,
                                                 ushort_t* __restrict__ out) {
  int idx = blockIdx.x * 256 + threadIdx.x;
  if (idx >= 16 * 48 * 48 * 512) return;
  int c = idx & 511;
  int px = idx >> 9;
  int x = px % 48; int rest = px / 48; int y = rest % 48; int b = rest / 48;
  int jy = y >> 1, jx = x >> 1;
  int y0, y1, x0, x1; float wy0, wy1, wx0, wx1;
  if (y & 1) { y0 = jy; y1 = (jy + 1 < 24) ? jy + 1 : 23; wy0 = 0.75f; wy1 = 0.25f; }
  else       { y0 = (jy > 0) ? jy - 1 : 0; y1 = jy; wy0 = 0.25f; wy1 = 0.75f; }
  if (x & 1) { x0 = jx; x1 = (jx + 1 < 24) ? jx + 1 : 23; wx0 = 0.75f; wx1 = 0.25f; }
  else       { x0 = (jx > 0) ? jx - 1 : 0; x1 = jx; wx0 = 0.25f; wx1 = 0.75f; }
  const float* p = in + ((size_t)b * 512 + c) * 576;
  float v = wy0 * (wx0 * p[y0 * 24 + x0] + wx1 * p[y0 * 24 + x1]) +
            wy1 * (wx0 * p[y1 * 24 + x0] + wx1 * p[y1 * 24 + x1]);
  out[(((size_t)b * 50 + y + 1) * 50 + (x + 1)) * 512 + c] = f2bf(v);
}

// up2: in bf16 NHWC (16,48,48,512) -> out bf16 NHWC padded (16,98,98,512) interior
__global__ __launch_bounds__(256) void upsample2(const ushort_t* __restrict__ in,
                                                 ushort_t* __restrict__ out) {
  int idx = blockIdx.x * 256 + threadIdx.x;
  if (idx >= 16 * 96 * 96 * 512) return;
  int c = idx & 511;
  int px = idx >> 9;
  int x = px % 96; int rest = px / 96; int y = rest % 96; int b = rest / 96;
  int jy = y >> 1, jx = x >> 1;
  int y0, y1, x0, x1; float wy0, wy1, wx0, wx1;
  if (y & 1) { y0 = jy; y1 = (jy + 1 < 48) ? jy + 1 : 47; wy0 = 0.75f; wy1 = 0.25f; }
  else       { y0 = (jy > 0) ? jy - 1 : 0; y1 = jy; wy0 = 0.25f; wy1 = 0.75f; }
  if (x & 1) { x0 = jx; x1 = (jx + 1 < 48) ? jx + 1 : 47; wx0 = 0.75f; wx1 = 0.25f; }
  else       { x0 = (jx > 0) ? jx - 1 : 0; x1 = jx; wx0 = 0.25f; wx1 = 0.75f; }
  const ushort_t* p = in + (size_t)b * 48 * 48 * 512 + c;
  float v = wy0 * (wx0 * bf2f(p[(y0 * 48 + x0) * 512]) + wx1 * bf2f(p[(y0 * 48 + x1) * 512])) +
            wy1 * (wx0 * bf2f(p[(y1 * 48 + x0) * 512]) + wx1 * bf2f(p[(y1 * 48 + x1) * 512]));
  out[(((size_t)b * 98 + y + 1) * 98 + (x + 1)) * 512 + c] = f2bf(v);
}

// ---------------------------------------------------------------------------
// Text GEMM via MFMA with hi/lo bf16 split (~f32 precision):
//   D = Ah.Bh + Ah.Bl + Al.Bh;  A = word (2048x768), B = txt_w (2432x768 pad)
// Output: n<2304 -> bf16 filters (B,Nc,9,256); n==2304 -> f32 dynbias.
// ---------------------------------------------------------------------------
__global__ __launch_bounds__(256, 2) void text_mfma(
    const ushort_t* __restrict__ wh, const ushort_t* __restrict__ wl,
    const ushort_t* __restrict__ th, const ushort_t* __restrict__ tl,
    const float* __restrict__ tb,
    ushort_t* __restrict__ wkbuf, float* __restrict__ dynbias) {
  __shared__ ushort_t Ahs[128 * 64];
  __shared__ ushort_t Als[128 * 64];
  __shared__ ushort_t Bhs[128 * 64];
  __shared__ ushort_t Bls[128 * 64];
  const int tid = threadIdx.x;
  const int lane = tid & 63;
  const int wid = tid >> 6;
  const int n0 = blockIdx.x * 128;
  const int m0 = blockIdx.y * 128;
  const int soff = ((lane & 7) ^ ((lane >> 3) & 7)) * 16;
  const int g8 = lane >> 3;
  const char *pah[4], *pal[4], *pbh[4], *pbl[4];
#pragma unroll
  for (int j = 0; j < 4; ++j) {
    int row = wid * 32 + j * 8 + g8;
    size_t ab = (size_t)(m0 + row) * 1536 + soff;
    pah[j] = (const char*)wh + ab;
    pal[j] = (const char*)wl + ab;
    size_t bb = (size_t)(n0 + row) * 1536 + soff;
    pbh[j] = (const char*)th + bb;
    pbl[j] = (const char*)tl + bb;
  }
  const int lr = lane & 15, hi4 = lane >> 4;
  const int cow = (wid >> 1) * 64;
  const int pxw = (wid & 1) * 64;
  int aoff[4], boff[4];
#pragma unroll
  for (int r = 0; r < 4; ++r) {
    int row = cow + r * 16 + lr;
    aoff[r] = row * 128 + ((hi4 ^ (row & 7)) * 16);
    row = pxw + r * 16 + lr;
    boff[r] = row * 128 + ((hi4 ^ (row & 7)) * 16);
  }
  f32x4 acc[4][4];
#pragma unroll
  for (int r = 0; r < 4; ++r)
#pragma unroll
    for (int q = 0; q < 4; ++q) acc[r][q] = (f32x4){0.f, 0.f, 0.f, 0.f};

#pragma unroll 1
  for (int k0 = 0; k0 < 768; k0 += 64) {
    const int kb = k0 * 2;
#pragma unroll
    for (int j = 0; j < 4; ++j) {
      const int ld = (wid * 4 + j) * 1024;
      GLOAD16(pah[j] + kb, (char*)Ahs + ld);
      GLOAD16(pal[j] + kb, (char*)Als + ld);
      GLOAD16(pbh[j] + kb, (char*)Bhs + ld);
      GLOAD16(pbl[j] + kb, (char*)Bls + ld);
    }
    __syncthreads();
#pragma unroll
    for (int ks = 0; ks < 2; ++ks) {
      const int kx = ks * 64;
      bf16x8 ah[4], al[4], bh[4], bl[4];
#pragma unroll
      for (int r = 0; r < 4; ++r) {
        ah[r] = *(const bf16x8*)((const char*)Ahs + (aoff[r] ^ kx));
        al[r] = *(const bf16x8*)((const char*)Als + (aoff[r] ^ kx));
        bh[r] = *(const bf16x8*)((const char*)Bhs + (boff[r] ^ kx));
        bl[r] = *(const bf16x8*)((const char*)Bls + (boff[r] ^ kx));
      }
#pragma unroll
      for (int r = 0; r < 4; ++r)
#pragma unroll
        for (int q = 0; q < 4; ++q)
          acc[r][q] = __builtin_amdgcn_mfma_f32_16x16x32_bf16(ah[r], bh[q], acc[r][q], 0, 0, 0);
#pragma unroll
      for (int r = 0; r < 4; ++r)
#pragma unroll
        for (int q = 0; q < 4; ++q)
          acc[r][q] = __builtin_amdgcn_mfma_f32_16x16x32_bf16(ah[r], bl[q], acc[r][q], 0, 0, 0);
#pragma unroll
      for (int r = 0; r < 4; ++r)
#pragma unroll
        for (int q = 0; q < 4; ++q)
          acc[r][q] = __builtin_amdgcn_mfma_f32_16x16x32_bf16(al[r], bh[q], acc[r][q], 0, 0, 0);
    }
    __syncthreads();
  }

  // epilogue: col(lane&15) = n, row(hi4*4+j) = m
#pragma unroll
  for (int r = 0; r < 4; ++r) {
#pragma unroll
    for (int q = 0; q < 4; ++q) {
      int n = n0 + pxw + q * 16 + lr;
      if (n > 2304) continue;
      float tbn = tb[n];
#pragma unroll
      for (int j = 0; j < 4; ++j) {
        int m = m0 + cow + r * 16 + hi4 * 4 + j;
        float v = acc[r][q][j] + tbn;
        if (n < 2304) {
          int c = n / 9, tap = n - c * 9;
          int nc = m >> 4, bb = m & 15;
          wkbuf[((size_t)bb * 128 + nc) * 2304 + tap * 256 + c] = f2bf(v);
        } else {
          dynbias[m] = v;
        }
      }
    }
  }
}

// ---------------------------------------------------------------------------
// NHWC implicit-GEMM conv, MFMA 16x16x32 bf16, global_load_lds staging,
// XOR-swizzled LDS (slot ^= row&7; linear dest + inverse-swizzled source).
//   in : NHWC, spatially pre-padded by 1 if KS==3 (zero border)
//   wt : (M, KS*KS, C) bf16, or (B, M, KS*KS, C) if PIW
// Block: 256 thr (4 waves), tile BM x BN, wave tile (BM/MW) x (BN/NW) = 128x64.
// EPI: 0 BN+ReLU->bf16 NHWC; 1 +bias->bf16 NHWC (OPAD: padded interior);
//      2 +dynbias->f32 NCHW.
// ---------------------------------------------------------------------------
template <int KS, int EPI, int BM, int BN, int MW, int NW, int H, int W, int C,
          int MOUT, bool PIW, bool OPAD>
__global__ __launch_bounds__(256, 2) void conv_mfma(
    const ushort_t* __restrict__ in, const ushort_t* __restrict__ wt,
    const float* __restrict__ p0, const float* __restrict__ p1,
    const float* __restrict__ p2, const float* __restrict__ p3,
    ushort_t* __restrict__ outb, float* __restrict__ outf) {
  constexpr int WAVES = 4;
  constexpr int AINST = BM / (8 * WAVES);
  constexpr int BINST = BN / (8 * WAVES);
  constexpr int MR = BM / MW / 16;
  constexpr int NR = BN / NW / 16;
  constexpr int KK = KS * KS;
  constexpr int PHI = (KS == 3) ? H + 2 : H;
  constexpr int PWI = (KS == 3) ? W + 2 : W;
  __shared__ ushort_t Asm[BM * 64];
  __shared__ ushort_t Bsm[BN * 64];

  const int tid = threadIdx.x;
  const int lane = tid & 63;
  const int wid = tid >> 6;
  const int p0t = blockIdx.x * BN;
  const int co0 = blockIdx.y * BM;
  const int b = blockIdx.z;

  // inverse swizzle on the global source; LDS dest stays lane-linear
  const int soff = ((lane & 7) ^ ((lane >> 3) & 7)) * 16;

  const char* wbase = (const char*)wt + (PIW ? (size_t)b * MOUT * KK * C * 2 : 0);
  const char* aptr[AINST];
#pragma unroll
  for (int j = 0; j < AINST; ++j) {
    int arow = wid * (AINST * 8) + j * 8 + (lane >> 3);
    aptr[j] = wbase + (size_t)(co0 + arow) * ((size_t)KK * C * 2) + soff;
  }
  const char* ibase = (const char*)in + (size_t)b * PHI * PWI * C * 2;
  const char* bptr[BINST];
#pragma unroll
  for (int i = 0; i < BINST; ++i) {
    int brow = wid * (BINST * 8) + i * 8 + (lane >> 3);
    int p = p0t + brow;
    int y = p / W, x = p % W;
    int off = (KS == 3) ? ((y + 1) * PWI + (x + 1)) : (y * W + x);
    bptr[i] = ibase + (size_t)off * C * 2 + soff;
  }

  const int lr = lane & 15, hi = lane >> 4;
  const int cow = (wid / NW) * (BM / MW);
  const int pxw = (wid % NW) * (BN / NW);
  int aoff[MR], boff[NR];
#pragma unroll
  for (int r = 0; r < MR; ++r) {
    int row = cow + r * 16 + lr;
    aoff[r] = row * 128 + ((hi ^ (row & 7)) * 16);
  }
#pragma unroll
  for (int q = 0; q < NR; ++q) {
    int row = pxw + q * 16 + lr;
    boff[q] = row * 128 + ((hi ^ (row & 7)) * 16);
  }

  f32x4 acc[MR][NR];
#pragma unroll
  for (int r = 0; r < MR; ++r)
#pragma unroll
    for (int q = 0; q < NR; ++q) acc[r][q] = (f32x4){0.f, 0.f, 0.f, 0.f};

#pragma unroll 1
  for (int tap = 0; tap < KK; ++tap) {
    const int toff = (KS == 3) ? ((tap / 3 - 1) * PWI + (tap % 3 - 1)) * C * 2 : 0;
#pragma unroll 1
    for (int c0 = 0; c0 < C; c0 += 64) {
      const int koff = (tap * C + c0) * 2;
#pragma unroll
      for (int j = 0; j < AINST; ++j)
        GLOAD16(aptr[j] + koff, (char*)Asm + (wid * AINST + j) * 1024);
#pragma unroll
      for (int i = 0; i < BINST; ++i)
        GLOAD16(bptr[i] + toff + c0 * 2, (char*)Bsm + (wid * BINST + i) * 1024);
      __syncthreads();
#pragma unroll
      for (int ks = 0; ks < 2; ++ks) {
        const int kx = ks * 64;  // slot^4 => byte^64
        bf16x8 af[MR], bfv[NR];
#pragma unroll
        for (int r = 0; r < MR; ++r)
          af[r] = *(const bf16x8*)((const char*)Asm + (aoff[r] ^ kx));
#pragma unroll
        for (int q = 0; q < NR; ++q)
          bfv[q] = *(const bf16x8*)((const char*)Bsm + (boff[q] ^ kx));
#pragma unroll
        for (int r = 0; r < MR; ++r)
#pragma unroll
          for (int q = 0; q < NR; ++q)
            acc[r][q] = __builtin_amdgcn_mfma_f32_16x16x32_bf16(af[r], bfv[q], acc[r][q], 0, 0, 0);
      }
      __syncthreads();
    }
  }

  // epilogue: D col=lane&15 (pixel), row=(lane>>4)*4+j (co)
#pragma unroll
  for (int r = 0; r < MR; ++r) {
    const int co = co0 + cow + r * 16 + hi * 4;
    float sc[4], sh[4];
#pragma unroll
    for (int j = 0; j < 4; ++j) {
      if (EPI == 0) {
        float inv = p0[co + j] * rsqrtf(p3[co + j] + 1e-5f);
        sc[j] = inv; sh[j] = p1[co + j] - p2[co + j] * inv;
      } else if (EPI == 1) {
        sc[j] = 1.f; sh[j] = p0[co + j];
      }
    }
#pragma unroll
    for (int q = 0; q < NR; ++q) {
      int p = p0t + pxw + q * 16 + lr;
      int y = p / W, x = p % W;
      if (EPI == 2) {
#pragma unroll
        for (int j = 0; j < 4; ++j) {
          float v = acc[r][q][j] + p0[(co + j) * 16 + b];
          outf[(((size_t)b * MOUT + co + j) * H + y) * W + x] = v;
        }
      } else {
        ushort_t pk[4];
#pragma unroll
        for (int j = 0; j < 4; ++j) {
          float v = acc[r][q][j] * sc[j] + sh[j];
          if (EPI == 0) v = fmaxf(v, 0.f);
          pk[j] = f2bf(v);
        }
        size_t oidx = OPAD
            ? (((size_t)b * (H + 2) + y + 1) * (W + 2) + x + 1) * MOUT + co
            : (((size_t)b * H + y) * W + x) * MOUT + co;
        *(uint2*)&outb[oidx] = *(const uint2*)pk;
      }
    }
  }
}

__global__ __launch_bounds__(256) void fill_zero(float* __restrict__ p, int n) {
  int i = blockIdx.x * 256 + threadIdx.x;
  if (i < n) p[i] = 0.f;
}

// ---------------------------------------------------------------------------
extern "C" void kernel_launch(void* const* d_in, const int* in_sizes, int n_in,
                              void* d_out, int out_size, void* d_ws, size_t ws_size,
                              hipStream_t stream) {
  (void)in_sizes; (void)n_in;
  const float* x       = (const float*)d_in[0];
  const float* word    = (const float*)d_in[1];
  const float* conv1_w = (const float*)d_in[2];
  const float* bn1_g   = (const float*)d_in[3];
  const float* bn1_b   = (const float*)d_in[4];
  const float* bn1_m   = (const float*)d_in[5];
  const float* bn1_v   = (const float*)d_in[6];
  const float* conv2_w = (const float*)d_in[7];
  const float* bn2_g   = (const float*)d_in[8];
  const float* bn2_b   = (const float*)d_in[9];
  const float* bn2_m   = (const float*)d_in[10];
  const float* bn2_v   = (const float*)d_in[11];
  const float* conv3_w = (const float*)d_in[12];
  const float* conv3_b = (const float*)d_in[13];
  const float* txt_w   = (const float*)d_in[14];
  const float* txt_b   = (const float*)d_in[15];
  float* out = (float*)d_out;

  char* ws = (char*)d_ws;
  size_t off = 0;
  auto alloc = [&](size_t bytes) -> void* {
    void* p = ws + off;
    off += bytes;
    off = (off + 255) & ~(size_t)255;
    return p;
  };
  // P0: up1 (16,50,50,512) -> up2 (16,98,98,512) -> vb (16,98,98,256); all NHWC
  ushort_t* P0  = (ushort_t*)alloc((size_t)16 * 98 * 98 * 512 * 2);  // 157.35 MB
  ushort_t* up1 = P0;
  ushort_t* up2 = P0;
  ushort_t* vb  = P0;
  ushort_t* a1  = (ushort_t*)alloc((size_t)16 * 48 * 48 * 512 * 2);  // 37.75 MB
  ushort_t* w1b = (ushort_t*)alloc((size_t)512 * 4608 * 2);
  ushort_t* w2b = (ushort_t*)alloc((size_t)256 * 4608 * 2);
  ushort_t* w3b = (ushort_t*)alloc((size_t)256 * 256 * 2);
  ushort_t* wkb = (ushort_t*)alloc((size_t)16 * 128 * 2304 * 2);
  float*    dyb = (float*)alloc((size_t)2048 * 4);
  ushort_t* whi = (ushort_t*)alloc((size_t)2048 * 768 * 2);
  ushort_t* wlo = (ushort_t*)alloc((size_t)2048 * 768 * 2);
  ushort_t* twh = (ushort_t*)alloc((size_t)2432 * 768 * 2);
  ushort_t* twl = (ushort_t*)alloc((size_t)2432 * 768 * 2);
  ushort_t* a2  = (ushort_t*)d_out;  // (16,96,96,256) bf16 == 75,497,472 B exact

  if (ws_size < off) {
    fill_zero<<<(out_size + 255) / 256, 256, 0, stream>>>(out, out_size);
    return;
  }

  // prep
  wprep<<<(512 * 4608 + 255) / 256, 256, 0, stream>>>(conv1_w, w1b, 512, 512, 9);
  wprep<<<(256 * 4608 + 255) / 256, 256, 0, stream>>>(conv2_w, w2b, 256, 512, 9);
  wprep<<<(256 * 256 + 255) / 256, 256, 0, stream>>>(conv3_w, w3b, 256, 256, 1);
  {
    long long nw = (long long)2048 * 768;
    fsplit<<<(int)((nw + 255) / 256), 256, 0, stream>>>(word, whi, wlo, 2048, nw);
    long long nt = (long long)2432 * 768;
    fsplit<<<(int)((nt + 255) / 256), 256, 0, stream>>>(txt_w, twh, twl, 2305, nt);
  }
  text_mfma<<<dim3(19, 16), 256, 0, stream>>>(whi, wlo, twh, twl, txt_b, wkb, dyb);

  // up1 (border + interior)
  {
    long long nbz = (long long)16 * (2 * 50 + 2 * 48) * 512;
    border_zero<<<(int)((nbz + 255) / 256), 256, 0, stream>>>(up1, 16, 50, 50, 512);
    int n = 16 * 48 * 48 * 512;
    upsample1<<<(n + 255) / 256, 256, 0, stream>>>(x, up1);
  }
  // conv1: (16,50,50,512) -> a1 (16,48,48,512)
  conv_mfma<3, 0, 256, 128, 2, 2, 48, 48, 512, 512, false, false>
      <<<dim3(18, 2, 16), 256, 0, stream>>>(up1, w1b, bn1_g, bn1_b, bn1_m, bn1_v,
                                            a1, nullptr);
  // up2 (border + interior)  [P0 reused; up1 dead]
  {
    long long nbz = (long long)16 * (2 * 98 + 2 * 96) * 512;
    border_zero<<<(int)((nbz + 255) / 256), 256, 0, stream>>>(up2, 16, 98, 98, 512);
    int n = 16 * 96 * 96 * 512;
    upsample2<<<(n + 255) / 256, 256, 0, stream>>>(a1, up2);
  }
  // conv2: (16,98,98,512) -> a2 (16,96,96,256) in d_out
  conv_mfma<3, 0, 256, 128, 2, 2, 96, 96, 512, 256, false, false>
      <<<dim3(72, 1, 16), 256, 0, stream>>>(up2, w2b, bn2_g, bn2_b, bn2_m, bn2_v,
                                            a2, nullptr);
  // vb border  [P0 reused; up2 dead]
  {
    long long nbz = (long long)16 * (2 * 98 + 2 * 96) * 256;
    border_zero<<<(int)((nbz + 255) / 256), 256, 0, stream>>>(vb, 16, 98, 98, 256);
  }
  // conv3 1x1: a2 -> vb (16,98,98,256) padded interior
  conv_mfma<1, 1, 256, 128, 2, 2, 96, 96, 256, 256, false, true>
      <<<dim3(72, 1, 16), 256, 0, stream>>>(a2, w3b, conv3_b, nullptr, nullptr, nullptr,
                                            vb, nullptr);
  // dynamic conv: vb -> out (B,128,96,96) f32 NCHW
  conv_mfma<3, 2, 128, 256, 1, 4, 96, 96, 256, 128, true, false>
      <<<dim3(36, 1, 16), 256, 0, stream>>>(vb, wkb, dyb, nullptr, nullptr, nullptr,
                                            nullptr, out);
}